// Round 1
// baseline (1012.323 us; speedup 1.0000x reference)
//
#include <hip/hip_runtime.h>

// GRU scan: B=2048, T=2048, D=3, H=32. out[b,t] = h_new[b,t][0].
// Round-4: full-K sigmoid rows + waitless DS ordering.
//  - lane = (unit, half); half0 owns r-row(unit), half1 owns z-row(unit),
//    each computed over the FULL 32-k hidden vector (no combine bpermute
//    before the sigmoid -> one LDS hop removed from the per-step chain).
//  - n-row stays K-half split (16 FMAs + one early, off-path bpermute).
//  - z crosses to half0 with one bpermute after the shared sigmoid.
//  - NO explicit lgkmcnt after h-write / x-staging: DS ops from one wave
//    are processed in order by the LDS pipe, so the next gather issues
//    immediately; compiler inserts counted lgkm waits before data use.
//  - x for chunk c+1 prefetched into registers during chunk c.

#define GRU_B 2048
#define GRU_T 2048
#define GRU_D 3
#define GRU_H 32
#define CHUNK 32  // timesteps per x-staging chunk (32*3 = 96 floats)

// s_waitcnt imm: lgkmcnt(0), vmcnt=63 (no wait), expcnt=7 (no wait)
#define WAIT_LGKM0 0xC07F

__device__ __forceinline__ float fast_sigmoid(float x) {
    float e = __expf(-x);                       // v_mul(log2e)+v_exp
    return __builtin_amdgcn_rcpf(1.0f + e);     // e=inf -> 0 (correct limit)
}
__device__ __forceinline__ float fast_tanh(float x) {
    float e = __expf(2.0f * x);                 // overflow -> inf -> tanh=1
    return 1.0f - 2.0f * __builtin_amdgcn_rcpf(e + 1.0f);
}
__device__ __forceinline__ float xor32(float v, int paddr) {
    return __int_as_float(__builtin_amdgcn_ds_bpermute(paddr, __float_as_int(v)));
}

__global__ __launch_bounds__(64, 2) void gru_scan_kernel(
    const float* __restrict__ inp,     // [B, T, D]
    const float* __restrict__ w_ih,    // [3H, D]
    const float* __restrict__ w_hh,    // [3H, H]
    const float* __restrict__ bias,    // [3H]
    const float* __restrict__ bias_n,  // [H]
    float* __restrict__ out)           // [B, T]
{
    // h2: [0..31] the live h vector (written by half0), [32..63] half1 dump.
    __shared__ __align__(16) float h2[2 * GRU_H];
    __shared__ __align__(16) float x_lds[CHUNK * GRU_D];

    const int lane  = threadIdx.x;       // 0..63
    const int unit  = lane & 31;         // hidden unit owned
    const int half  = lane >> 5;         // 0: r-rows, 1: z-rows
    const int b     = blockIdx.x;
    const int paddr = (lane ^ 32) << 2;  // bpermute byte addr (hoisted)

    const int rowS = unit + 32 * half;   // my sigmoid gate row (r / z)
    const int rowN = 2 * GRU_H + unit;   // n gate row
    const int kofs = 16 * half;          // my n-row K-half columns

    // Weights: full 32-k sigmoid row, 16-k n half-row.
    float ws[32], wn[16];
    {
        const float4* ps = (const float4*)(w_hh + (size_t)rowS * GRU_H);
#pragma unroll
        for (int q = 0; q < 8; ++q) {
            float4 v = ps[q];
            ws[4*q+0]=v.x; ws[4*q+1]=v.y; ws[4*q+2]=v.z; ws[4*q+3]=v.w;
        }
        const float4* pn = (const float4*)(w_hh + (size_t)rowN * GRU_H + kofs);
#pragma unroll
        for (int q = 0; q < 4; ++q) {
            float4 v = pn[q];
            wn[4*q+0]=v.x; wn[4*q+1]=v.y; wn[4*q+2]=v.z; wn[4*q+3]=v.w;
        }
    }
    float wis[GRU_D], win[GRU_D];
#pragma unroll
    for (int d = 0; d < GRU_D; ++d) {
        wis[d] = w_ih[(size_t)rowS * GRU_D + d];
        win[d] = w_ih[(size_t)rowN * GRU_D + d];
    }
    const float bS = bias[rowS];                 // r-bias (half0) / z-bias (half1)
    const float bN = bias[rowN] + bias_n[unit];  // n-gate bias, bias_n folded in

    const float* xb = inp + (size_t)b * GRU_T * GRU_D;
    float*       ob = out + (size_t)b * GRU_T;

    float h = 0.0f;       // own unit's h (valid trajectory in half0; finite in half1)
    float outreg = 0.0f;  // chunk-local captured output (lane t <- step t)

    h2[lane] = 0.0f;      // zero live + dump
    __builtin_amdgcn_s_waitcnt(WAIT_LGKM0);      // once, before first gather

    const float4* hv  = (const float4*)h2;          // full gather, broadcast
    const float4* hvn = (const float4*)(h2 + kofs); // n-half gather (2 bcast groups)
    const int wbase = unit + 32 * half;             // half0 -> live, half1 -> dump

    // x prefetch registers (chunk 0 loaded up front)
    float xr0 = xb[lane];
    float xr1 = (lane < CHUNK * GRU_D - 64) ? xb[64 + lane] : 0.0f;

    for (int c = 0; c < GRU_T / CHUNK; ++c) {
        // ---- stage current chunk's x (regs -> LDS); prefetch next chunk ----
        x_lds[lane] = xr0;
        if (lane < CHUNK * GRU_D - 64) x_lds[64 + lane] = xr1;
        if (c + 1 < GRU_T / CHUNK) {
            const int nb = (c + 1) * (CHUNK * GRU_D);
            xr0 = xb[nb + lane];
            xr1 = (lane < CHUNK * GRU_D - 64) ? xb[nb + 64 + lane] : 0.0f;
        }
        // staging writes precede step x-reads in the same-wave DS queue: no wait.

#pragma unroll 8
        for (int s = 0; s < CHUNK; ++s) {
            // h all-gather: 8 x ds_read_b128 broadcast (whole wave, same addr)
            float hk[32];
#pragma unroll
            for (int q = 0; q < 8; ++q) {
                float4 v = hv[q];
                hk[4*q+0]=v.x; hk[4*q+1]=v.y; hk[4*q+2]=v.z; hk[4*q+3]=v.w;
            }
            // n-half gather: 4 x ds_read_b128 (compile-time reg indices need
            // a separate load at runtime base h2+kofs; avoids scratch)
            float hn[16];
#pragma unroll
            for (int q = 0; q < 4; ++q) {
                float4 v = hvn[q];
                hn[4*q+0]=v.x; hn[4*q+1]=v.y; hn[4*q+2]=v.z; hn[4*q+3]=v.w;
            }
            const float x0 = x_lds[3*s+0];
            const float x1 = x_lds[3*s+1];
            const float x2 = x_lds[3*s+2];

            // input projections (off critical path)
            const float aS = fmaf(wis[2], x2, fmaf(wis[1], x1, fmaf(wis[0], x0, bS)));
            const float aN = fmaf(win[2], x2, fmaf(win[1], x1, fmaf(win[0], x0, bN)));

            // n-row K-half partial first -> its combine bpermute issues early
            float N0=0.0f, N1=0.0f, N2=0.0f, N3=0.0f;
#pragma unroll
            for (int q = 0; q < 4; ++q) {
                N0 = fmaf(wn[4*q+0], hn[4*q+0], N0);
                N1 = fmaf(wn[4*q+1], hn[4*q+1], N1);
                N2 = fmaf(wn[4*q+2], hn[4*q+2], N2);
                N3 = fmaf(wn[4*q+3], hn[4*q+3], N3);
            }
            const float Np = (N0 + N1) + (N2 + N3);
            const float gN = Np + xor32(Np, paddr);   // off-path LDS hop

            // full-K sigmoid row, 4-way split accumulators (short dep chain)
            float S0=aS, S1=0.0f, S2=0.0f, S3=0.0f;
#pragma unroll
            for (int q = 0; q < 8; ++q) {
                S0 = fmaf(ws[4*q+0], hk[4*q+0], S0);
                S1 = fmaf(ws[4*q+1], hk[4*q+1], S1);
                S2 = fmaf(ws[4*q+2], hk[4*q+2], S2);
                S3 = fmaf(ws[4*q+3], hk[4*q+3], S3);
            }
            const float S = (S0 + S1) + (S2 + S3);

            const float sg = fast_sigmoid(S);        // half0: r, half1: z
            const float zc = xor32(sg, paddr);       // half0 receives z
            const float n  = fast_tanh(fmaf(sg, gN, aN));   // valid in half0
            const float hnew = fmaf(zc, h - n, n);          // (1-z)*n + z*h, half0

            // hk[0] = h[0] BEFORE this step = output of step s-1
            if (lane == s - 1) outreg = hk[0];

            h = hnew;
            h2[wbase] = h;   // half0: live vector; half1: dump.
            // Next gather is ordered behind this write by the DS queue: no wait.
        }

        // step-31 output: h[0] after last step (DS-ordered read, compiler waits)
        {
            const float h0 = h2[0];
            if (lane == CHUNK - 1) outreg = h0;
        }
        if (lane < CHUNK) ob[c * CHUNK + lane] = outreg;  // coalesced 128B store
    }
}

extern "C" void kernel_launch(void* const* d_in, const int* in_sizes, int n_in,
                              void* d_out, int out_size, void* d_ws, size_t ws_size,
                              hipStream_t stream) {
    const float* inp    = (const float*)d_in[0];
    const float* w_ih   = (const float*)d_in[1];
    const float* w_hh   = (const float*)d_in[2];
    const float* bias   = (const float*)d_in[3];
    const float* bias_n = (const float*)d_in[4];
    float* out = (float*)d_out;

    dim3 grid(GRU_B);
    dim3 block(64);
    gru_scan_kernel<<<grid, block, 0, stream>>>(inp, w_ih, w_hh, bias, bias_n, out);
}

// Round 2
// 686.095 us; speedup vs baseline: 1.4755x; 1.4755x over previous
//
#include <hip/hip_runtime.h>

// GRU scan: B=2048, T=2048, D=3, H=32. out[b,t] = h_new[b,t][0].
// Round-5: LDS-pipe decongestion. Round-4 showed the kernel is LDS-pipe
// THROUGHPUT bound per CU (8 waves share it): +8 bcast b128/step cost
// +395 cy/step (6 cy/read), and round-3's 3 ds_bpermutes cost ~20 cy each
// (~60 of ~104 DS-cycles/wave/step). This round:
//  - round-3 half-K structure (4 bcast ds_read_b128, 48 FMA) restored;
//  - all three lane^32 exchanges moved OFF the LDS pipe:
//    v_permlane32_swap_b32 (VALU) + cndmask. Output-half semantics are
//    probed at runtime (template<MODE>, ds_bpermute fallback = MODE 2);
//  - single h copy: write is h2[lane] (conflict-free b32), halves gather
//    their K-half from h2[16*half .. +15] (two disjoint broadcast groups);
//  - waitless same-wave DS ordering kept from round-4 (verified passing).
// Predicted DS/step/wave ~40 cy -> 320/CU; VALU-bound ~360 cy/SIMD/step.

#define GRU_B 2048
#define GRU_T 2048
#define GRU_D 3
#define GRU_H 32
#define CHUNK 32  // timesteps per x-staging chunk (32*3 = 96 floats)

// s_waitcnt imm: lgkmcnt(0), vmcnt=63 (no wait), expcnt=7 (no wait)
#define WAIT_LGKM0 0xC07F

typedef unsigned int uint2v __attribute__((ext_vector_type(2)));

__device__ __forceinline__ float fast_sigmoid(float x) {
    float e = __expf(-x);                       // v_mul(log2e)+v_exp
    return __builtin_amdgcn_rcpf(1.0f + e);     // e=inf -> 0 (correct limit)
}
__device__ __forceinline__ float fast_tanh(float x) {
    float e = __expf(2.0f * x);                 // overflow -> inf -> tanh=1
    return 1.0f - 2.0f * __builtin_amdgcn_rcpf(e + 1.0f);
}

// lane^32 exchange. MODE 0/1: permlane32_swap (VALU pipe; the two modes are
// the two possible output-half orderings). MODE 2: ds_bpermute (LDS pipe).
template<int MODE>
__device__ __forceinline__ float xswap(float v, int lane, int paddr) {
    if constexpr (MODE == 2) {
        return __int_as_float(__builtin_amdgcn_ds_bpermute(paddr, __float_as_int(v)));
    } else {
        uint2v r = __builtin_amdgcn_permlane32_swap(
            __float_as_uint(v), __float_as_uint(v), false, false);
        const unsigned lo = (MODE == 0) ? r.x : r.y;  // value for lanes 0..31
        const unsigned hi = (MODE == 0) ? r.y : r.x;  // value for lanes 32..63
        return __uint_as_float((lane < 32) ? lo : hi);
    }
}

template<int MODE>
__device__ __forceinline__ void gru_loop(
    const float* __restrict__ xb, float* __restrict__ ob,
    float* __restrict__ h2, float* __restrict__ x_lds,
    const float* __restrict__ wa, const float* __restrict__ wb,
    const float* __restrict__ wc,
    const float* __restrict__ wia, const float* __restrict__ wic,
    float bA, float bC, int lane, int half, int paddr)
{
    // gather base: half0 reads h[0..15] (bytes 0..63, banks 0-15);
    // half1 reads h[16..31] (bytes 64..127, banks 16-31). Two broadcast
    // groups on disjoint banks -> conflict-free.
    const float4* hv = (const float4*)(h2 + 16 * half);

    float h = 0.0f;       // own unit's h (valid trajectory in half0)
    float outreg = 0.0f;  // chunk-local captured output (lane t <- step t)

    // x prefetch registers (chunk 0 loaded up front)
    float xr0 = xb[lane];
    float xr1 = (lane < CHUNK * GRU_D - 64) ? xb[64 + lane] : 0.0f;

    for (int c = 0; c < GRU_T / CHUNK; ++c) {
        // ---- stage current chunk's x (regs -> LDS); prefetch next chunk ----
        x_lds[lane] = xr0;
        if (lane < CHUNK * GRU_D - 64) x_lds[64 + lane] = xr1;
        if (c + 1 < GRU_T / CHUNK) {
            const int nb = (c + 1) * (CHUNK * GRU_D);
            xr0 = xb[nb + lane];
            xr1 = (lane < CHUNK * GRU_D - 64) ? xb[nb + 64 + lane] : 0.0f;
        }
        // staging writes precede step x-reads in the same-wave DS queue: no wait.

#pragma unroll 8
        for (int s = 0; s < CHUNK; ++s) {
            // h K-half gather: 4 x ds_read_b128, broadcast per half
            float hk[16];
#pragma unroll
            for (int q = 0; q < 4; ++q) {
                float4 v = hv[q];
                hk[4*q+0]=v.x; hk[4*q+1]=v.y; hk[4*q+2]=v.z; hk[4*q+3]=v.w;
            }
            const float x0 = x_lds[3*s+0];
            const float x1 = x_lds[3*s+1];
            const float x2 = x_lds[3*s+2];

            // input projections: my sigmoid gate + n gate (6 FMAs)
            const float aM = fmaf(wia[2], x2, fmaf(wia[1], x1, fmaf(wia[0], x0, bA)));
            const float aN = fmaf(wic[2], x2, fmaf(wic[1], x1, fmaf(wic[0], x0, bC)));

            // K-half partials: my gate (A), other gate (B, to send), n gate (C)
            float A0=0.f, A1=0.f, B0=0.f, B1=0.f, C0=0.f, C1=0.f;
#pragma unroll
            for (int k = 0; k < 16; k += 2) {
                A0 = fmaf(wa[k],   hk[k],   A0);
                A1 = fmaf(wa[k+1], hk[k+1], A1);
                B0 = fmaf(wb[k],   hk[k],   B0);
                B1 = fmaf(wb[k+1], hk[k+1], B1);
                C0 = fmaf(wc[k],   hk[k],   C0);
                C1 = fmaf(wc[k+1], hk[k+1], C1);
            }
            const float A  = A0 + A1;
            const float Bp = B0 + B1;
            const float Cp = C0 + C1;

            // combine: my full sigmoid-gate sum = own partial + partner's
            const float gM = A  + xswap<MODE>(Bp, lane, paddr);
            const float gN = Cp + xswap<MODE>(Cp, lane, paddr);

            const float sg  = fast_sigmoid(aM + gM);       // half0: r, half1: z
            const float zsw = xswap<MODE>(sg, lane, paddr); // half0 receives z
            const float n   = fast_tanh(fmaf(sg, gN, aN));  // valid in half0
            const float hnew = fmaf(zsw, h - n, n);         // (1-z)*n + z*h

            // hk[0] in half0 = h[0] BEFORE this step = output of step s-1
            if (lane == s - 1) outreg = hk[0];

            h = hnew;
            h2[lane] = h;   // half0: live vector [0..31]; half1: dump [32..63]
            // Next gather is ordered behind this write by the DS queue: no wait.
        }

        // step-31 output: h[0] after last step (DS-ordered read)
        {
            const float h0 = h2[0];
            if (lane == CHUNK - 1) outreg = h0;
        }
        if (lane < CHUNK) ob[c * CHUNK + lane] = outreg;  // coalesced 128B store
    }
}

__global__ __launch_bounds__(64, 2) void gru_scan_kernel(
    const float* __restrict__ inp,     // [B, T, D]
    const float* __restrict__ w_ih,    // [3H, D]
    const float* __restrict__ w_hh,    // [3H, H]
    const float* __restrict__ bias,    // [3H]
    const float* __restrict__ bias_n,  // [H]
    float* __restrict__ out)           // [B, T]
{
    // h2 (floats): [0..31] live h vector (written by half0), [32..63] dump.
    __shared__ __align__(16) float h2[2 * GRU_H];
    __shared__ __align__(16) float x_lds[CHUNK * GRU_D];

    const int lane  = threadIdx.x;       // 0..63
    const int unit  = lane & 31;         // hidden unit owned
    const int half  = lane >> 5;         // K-half: 0 -> k 0..15, 1 -> k 16..31
    const int b     = blockIdx.x;
    const int paddr = (lane ^ 32) << 2;  // bpermute byte addr (fallback path)

    // Gate-row assignment (sigma-split):
    //  rowA = my sigmoid gate (r for half0, z for half1)
    //  rowB = the other sigmoid gate (partial computed only to SEND)
    //  rowC = n gate
    const int rowA = unit + 32 * half;
    const int rowB = unit + 32 * (1 - half);
    const int rowC = 2 * GRU_H + unit;
    const int kofs = 16 * half;          // my K-half columns

    float wa[16], wb[16], wc[16];
    {
        const float4* pa = (const float4*)(w_hh + (size_t)rowA * GRU_H + kofs);
        const float4* pb = (const float4*)(w_hh + (size_t)rowB * GRU_H + kofs);
        const float4* pc = (const float4*)(w_hh + (size_t)rowC * GRU_H + kofs);
#pragma unroll
        for (int q = 0; q < 4; ++q) {
            float4 Av = pa[q], Bv = pb[q], Cv = pc[q];
            wa[4*q+0]=Av.x; wa[4*q+1]=Av.y; wa[4*q+2]=Av.z; wa[4*q+3]=Av.w;
            wb[4*q+0]=Bv.x; wb[4*q+1]=Bv.y; wb[4*q+2]=Bv.z; wb[4*q+3]=Bv.w;
            wc[4*q+0]=Cv.x; wc[4*q+1]=Cv.y; wc[4*q+2]=Cv.z; wc[4*q+3]=Cv.w;
        }
    }
    float wia[GRU_D], wic[GRU_D];
#pragma unroll
    for (int d = 0; d < GRU_D; ++d) {
        wia[d] = w_ih[(size_t)rowA * GRU_D + d];
        wic[d] = w_ih[(size_t)rowC * GRU_D + d];
    }
    const float bA = bias[rowA];                 // r-bias (half0) / z-bias (half1)
    const float bC = bias[rowC] + bias_n[unit];  // n-gate bias, bias_n folded in

    const float* xb = inp + (size_t)b * GRU_T * GRU_D;
    float*       ob = out + (size_t)b * GRU_T;

    h2[lane] = 0.0f;      // zero live + dump
    __builtin_amdgcn_s_waitcnt(WAIT_LGKM0);      // once, before first gather

    // ---- probe permlane32_swap output-half ordering (uniform, one-time) ----
    int mode;
    {
        const unsigned pl = (unsigned)lane;
        uint2v pr = __builtin_amdgcn_permlane32_swap(pl, pl, false, false);
        const unsigned want = (unsigned)(lane ^ 32);
        const unsigned selA = (lane < 32) ? pr.x : pr.y;
        const unsigned selB = (lane < 32) ? pr.y : pr.x;
        if (__ballot(selA == want) == 0xFFFFFFFFFFFFFFFFULL)      mode = 0;
        else if (__ballot(selB == want) == 0xFFFFFFFFFFFFFFFFULL) mode = 1;
        else                                                      mode = 2;
    }

    if (mode == 0)
        gru_loop<0>(xb, ob, h2, x_lds, wa, wb, wc, wia, wic, bA, bC, lane, half, paddr);
    else if (mode == 1)
        gru_loop<1>(xb, ob, h2, x_lds, wa, wb, wc, wia, wic, bA, bC, lane, half, paddr);
    else
        gru_loop<2>(xb, ob, h2, x_lds, wa, wb, wc, wia, wic, bA, bC, lane, half, paddr);
}

extern "C" void kernel_launch(void* const* d_in, const int* in_sizes, int n_in,
                              void* d_out, int out_size, void* d_ws, size_t ws_size,
                              hipStream_t stream) {
    const float* inp    = (const float*)d_in[0];
    const float* w_ih   = (const float*)d_in[1];
    const float* w_hh   = (const float*)d_in[2];
    const float* bias   = (const float*)d_in[3];
    const float* bias_n = (const float*)d_in[4];
    float* out = (float*)d_out;

    dim3 grid(GRU_B);
    dim3 block(64);
    gru_scan_kernel<<<grid, block, 0, stream>>>(inp, w_ih, w_hh, bias, bias_n, out);
}